// Round 3
// baseline (224.179 us; speedup 1.0000x reference)
//
#include <hip/hip_runtime.h>

typedef unsigned int u32;

constexpr int B = 128, NN = 400, FEAT = 256, DEG = 64;
constexpr int N = B * NN;          // 51200
constexpr int E = B * NN * DEG;    // 3276800
constexpr int EPG = NN * DEG;      // 25600 edges per graph
constexpr int SPL = 4;             // edge splits per graph
constexpr int EPS = EPG / SPL;     // 6400 edges per split-block

__device__ __forceinline__ float lrelu(float t) { return t > 0.f ? t : 0.01f * t; }

// K1: h0 = leaky_relu(x @ fc1_w.T + fc1_b)   [128,400]
// grid 256 (2 per batch row), block 256
__global__ void k_h0(const float* __restrict__ x, const float* __restrict__ fc1w,
                     const float* __restrict__ fc1b, float* __restrict__ h0g) {
    int b  = blockIdx.x >> 1;
    int nb = (blockIdx.x & 1) * 200;
    __shared__ float xs[FEAT];
    if (threadIdx.x < FEAT) xs[threadIdx.x] = x[b * FEAT + threadIdx.x];
    __syncthreads();
    if (threadIdx.x < 200) {
        int n = nb + threadIdx.x;
        const float4* w4 = reinterpret_cast<const float4*>(fc1w + n * FEAT);
        float s = 0.f;
        #pragma unroll 4
        for (int k4 = 0; k4 < FEAT / 4; ++k4) {
            float4 p = w4[k4];
            const float* xk = xs + k4 * 4;
            s += p.x * xk[0] + p.y * xk[1] + p.z * xk[2] + p.w * xk[3];
        }
        h0g[b * NN + n] = lrelu(s + fc1b[n]);
    }
}

// K2: conv1 edge aggregation (scalar channel). h0 staged in LDS, streaming edge reads.
// grid 512 (128 graphs x 4 splits), block 1024
__global__ void __launch_bounds__(1024, 2)
k_conv1(const int* __restrict__ ei, const float* __restrict__ ea,
        const float* __restrict__ h0g,
        float* __restrict__ agg1p, float* __restrict__ cntp) {
    int b = blockIdx.x >> 2, sp = blockIdx.x & 3;
    __shared__ float h0s[NN];
    __shared__ float a1[NN];
    __shared__ float ct[NN];
    int boff = b * NN;
    if (threadIdx.x < NN) {
        h0s[threadIdx.x] = h0g[boff + threadIdx.x];
        a1[threadIdx.x] = 0.f;
        ct[threadIdx.x] = 0.f;
    }
    __syncthreads();
    int ebase = b * EPG + sp * EPS;
    for (int e = ebase + (int)threadIdx.x; e < ebase + EPS; e += 1024) {
        int s = ei[e] - boff;
        int d = ei[E + e] - boff;
        float w = ea[e];
        atomicAdd(&a1[d], w * h0s[s]);
        atomicAdd(&ct[d], 1.0f);
    }
    __syncthreads();
    if (threadIdx.x < NN) {
        agg1p[sp * N + boff + threadIdx.x] = a1[threadIdx.x];
        cntp[sp * N + boff + threadIdx.x]  = ct[threadIdx.x];
    }
}

// K3: h1[n][8] = leaky(agg1/cnt * Wrel1 + brel1 + h0 * Wroot1); also combined cnt
// grid 200, block 256
__global__ void k_h1(const float* __restrict__ agg1p, const float* __restrict__ cntp,
                     const float* __restrict__ h0g,
                     const float* __restrict__ Wr1, const float* __restrict__ br1,
                     const float* __restrict__ Wo1,
                     float* __restrict__ h1g, float* __restrict__ cntg) {
    int n = blockIdx.x * 256 + threadIdx.x;
    float a = 0.f, c = 0.f;
    #pragma unroll
    for (int sp = 0; sp < SPL; ++sp) { a += agg1p[sp * N + n]; c += cntp[sp * N + n]; }
    cntg[n] = c;
    a /= fmaxf(c, 1.f);
    float h0 = h0g[n];
    float v[8];
    #pragma unroll
    for (int k = 0; k < 8; ++k)
        v[k] = lrelu(a * Wr1[k] + br1[k] + h0 * Wo1[k]);
    float4* o = reinterpret_cast<float4*>(h1g + n * 8);
    o[0] = make_float4(v[0], v[1], v[2], v[3]);
    o[1] = make_float4(v[4], v[5], v[6], v[7]);
}

// K4: conv2 edge aggregation (8 channels). h1 staged in LDS; one edge per thread.
// grid 512, block 1024
__global__ void __launch_bounds__(1024, 2)
k_conv2(const int* __restrict__ ei, const float* __restrict__ ea,
        const float* __restrict__ h1g, float* __restrict__ agg2p) {
    int b = blockIdx.x >> 2, sp = blockIdx.x & 3;
    __shared__ alignas(16) float h1s[NN * 8];
    __shared__ float a2[NN * 8];
    int boff = b * NN;
    {
        const float4* src = reinterpret_cast<const float4*>(h1g + (size_t)boff * 8);
        float4* dst = reinterpret_cast<float4*>(h1s);
        if (threadIdx.x < NN * 2) dst[threadIdx.x] = src[threadIdx.x];
        for (int i = threadIdx.x; i < NN * 8; i += 1024) a2[i] = 0.f;
    }
    __syncthreads();
    int ebase = b * EPG + sp * EPS;
    for (int e = ebase + (int)threadIdx.x; e < ebase + EPS; e += 1024) {
        int s = ei[e] - boff;
        int d = ei[E + e] - boff;
        float w = ea[e];
        const float4* hv = reinterpret_cast<const float4*>(h1s + s * 8);
        float4 h0v = hv[0], h1v = hv[1];
        float* ap = a2 + d * 8;
        atomicAdd(ap + 0, w * h0v.x);
        atomicAdd(ap + 1, w * h0v.y);
        atomicAdd(ap + 2, w * h0v.z);
        atomicAdd(ap + 3, w * h0v.w);
        atomicAdd(ap + 4, w * h1v.x);
        atomicAdd(ap + 5, w * h1v.y);
        atomicAdd(ap + 6, w * h1v.z);
        atomicAdd(ap + 7, w * h1v.w);
    }
    __syncthreads();
    for (int i = threadIdx.x; i < NN * 8; i += 1024)
        agg2p[sp * (8 * N) + boff * 8 + i] = a2[i];
}

// K5: out[b,i,j] = sigmoid(0.5*(z_i.m_j + z_j.m_i + bb[i] + bb[j]))
// z = [agg2/cnt (8), h1 (8)], m_j = [Wrel2[j,:], Wroot2[j,:]]
// grid 512 (128 graphs x 4 row-blocks of 100), block 512
__global__ void __launch_bounds__(512, 4)
k_out(const float* __restrict__ h1g, const float* __restrict__ agg2p,
      const float* __restrict__ cntg,
      const float* __restrict__ Wr2, const float* __restrict__ br2,
      const float* __restrict__ Wo2, float* __restrict__ out) {
    int b = blockIdx.x >> 2, rb = blockIdx.x & 3;
    __shared__ alignas(16) float Zt[16 * NN];
    __shared__ alignas(16) float Mt[16 * NN];
    __shared__ float bbs[NN];

    int j = threadIdx.x;
    if (j < NN) {
        int n = b * NN + j;
        float cm = fmaxf(cntg[n], 1.f);
        float4 sA = make_float4(0, 0, 0, 0), sB = make_float4(0, 0, 0, 0);
        #pragma unroll
        for (int sp = 0; sp < SPL; ++sp) {
            const float4* ap = reinterpret_cast<const float4*>(agg2p + (size_t)sp * 8 * N + (size_t)n * 8);
            float4 p0 = ap[0], p1 = ap[1];
            sA.x += p0.x; sA.y += p0.y; sA.z += p0.z; sA.w += p0.w;
            sB.x += p1.x; sB.y += p1.y; sB.z += p1.z; sB.w += p1.w;
        }
        float inv = 1.f / cm;
        Zt[0 * NN + j] = sA.x * inv; Zt[1 * NN + j] = sA.y * inv;
        Zt[2 * NN + j] = sA.z * inv; Zt[3 * NN + j] = sA.w * inv;
        Zt[4 * NN + j] = sB.x * inv; Zt[5 * NN + j] = sB.y * inv;
        Zt[6 * NN + j] = sB.z * inv; Zt[7 * NN + j] = sB.w * inv;
        const float4* hv = reinterpret_cast<const float4*>(h1g + (size_t)n * 8);
        float4 h0v = hv[0], h1v = hv[1];
        Zt[ 8 * NN + j] = h0v.x; Zt[ 9 * NN + j] = h0v.y;
        Zt[10 * NN + j] = h0v.z; Zt[11 * NN + j] = h0v.w;
        Zt[12 * NN + j] = h1v.x; Zt[13 * NN + j] = h1v.y;
        Zt[14 * NN + j] = h1v.z; Zt[15 * NN + j] = h1v.w;
        const float* wr = Wr2 + j * 8;
        const float* wo = Wo2 + j * 8;
        #pragma unroll
        for (int k = 0; k < 8; ++k) {
            Mt[k * NN + j]       = wr[k];
            Mt[(8 + k) * NN + j] = wo[k];
        }
        bbs[j] = br2[j];
    }
    __syncthreads();

    for (int t = threadIdx.x; t < 25 * 50; t += 512) {
        int ti = t % 25, tj = t / 25;
        int i0 = rb * 100 + ti * 4;
        int j0 = tj * 8;
        float acc[4][8];
        #pragma unroll
        for (int r = 0; r < 4; ++r)
            #pragma unroll
            for (int cc = 0; cc < 8; ++cc) acc[r][cc] = 0.f;

        #pragma unroll
        for (int k = 0; k < 16; ++k) {
            const float* zr = Zt + k * NN;
            const float* mr = Mt + k * NN;
            float4 az  = *reinterpret_cast<const float4*>(zr + i0);
            float4 am  = *reinterpret_cast<const float4*>(mr + i0);
            float4 bz0 = *reinterpret_cast<const float4*>(zr + j0);
            float4 bz1 = *reinterpret_cast<const float4*>(zr + j0 + 4);
            float4 bm0 = *reinterpret_cast<const float4*>(mr + j0);
            float4 bm1 = *reinterpret_cast<const float4*>(mr + j0 + 4);
            float ar[4]  = {az.x, az.y, az.z, az.w};
            float amr[4] = {am.x, am.y, am.z, am.w};
            float bzv[8] = {bz0.x, bz0.y, bz0.z, bz0.w, bz1.x, bz1.y, bz1.z, bz1.w};
            float bmv[8] = {bm0.x, bm0.y, bm0.z, bm0.w, bm1.x, bm1.y, bm1.z, bm1.w};
            #pragma unroll
            for (int r = 0; r < 4; ++r)
                #pragma unroll
                for (int cc = 0; cc < 8; ++cc)
                    acc[r][cc] += ar[r] * bmv[cc] + amr[r] * bzv[cc];
        }

        float bi[4], bj[8];
        #pragma unroll
        for (int r = 0; r < 4; ++r) bi[r] = bbs[i0 + r];
        #pragma unroll
        for (int cc = 0; cc < 8; ++cc) bj[cc] = bbs[j0 + cc];

        size_t obase = (size_t)b * NN * NN;
        #pragma unroll
        for (int r = 0; r < 4; ++r) {
            float vout[8];
            #pragma unroll
            for (int cc = 0; cc < 8; ++cc) {
                float xv = 0.5f * (acc[r][cc] + bi[r] + bj[cc]);
                vout[cc] = 1.f / (1.f + __expf(-xv));
            }
            float* op = out + obase + (size_t)(i0 + r) * NN + j0;
            *reinterpret_cast<float4*>(op)     = make_float4(vout[0], vout[1], vout[2], vout[3]);
            *reinterpret_cast<float4*>(op + 4) = make_float4(vout[4], vout[5], vout[6], vout[7]);
        }
    }
}

extern "C" void kernel_launch(void* const* d_in, const int* in_sizes, int n_in,
                              void* d_out, int out_size, void* d_ws, size_t ws_size,
                              hipStream_t stream) {
    const float* x    = (const float*)d_in[0];
    const int*   ei   = (const int*)d_in[1];
    const float* ea   = (const float*)d_in[2];
    const float* fc1w = (const float*)d_in[3];
    const float* fc1b = (const float*)d_in[4];
    const float* Wr1  = (const float*)d_in[5];
    const float* br1  = (const float*)d_in[6];
    const float* Wo1  = (const float*)d_in[7];
    const float* Wr2  = (const float*)d_in[8];
    const float* br2  = (const float*)d_in[9];
    const float* Wo2  = (const float*)d_in[10];
    float* out = (float*)d_out;

    float* ws    = (float*)d_ws;
    float* h0g   = ws;             // N
    float* cntg  = ws + N;         // N
    float* h1g   = ws + 2 * N;     // 8N
    float* agg1p = ws + 10 * N;    // 4N
    float* cntp  = ws + 14 * N;    // 4N
    float* agg2p = ws + 18 * N;    // 32N  (total 50N floats = 10.24 MB)

    hipLaunchKernelGGL(k_h0,    dim3(256), dim3(256),  0, stream, x, fc1w, fc1b, h0g);
    hipLaunchKernelGGL(k_conv1, dim3(512), dim3(1024), 0, stream, ei, ea, h0g, agg1p, cntp);
    hipLaunchKernelGGL(k_h1,    dim3(200), dim3(256),  0, stream, agg1p, cntp, h0g, Wr1, br1, Wo1, h1g, cntg);
    hipLaunchKernelGGL(k_conv2, dim3(512), dim3(1024), 0, stream, ei, ea, h1g, agg2p);
    hipLaunchKernelGGL(k_out,   dim3(512), dim3(512),  0, stream, h1g, agg2p, cntg, Wr2, br2, Wo2, out);
}

// Round 4
// 107.386 us; speedup vs baseline: 2.0876x; 2.0876x over previous
//
#include <hip/hip_runtime.h>

typedef unsigned int u32;

constexpr int B = 128, NN = 400, FEAT = 256, DEG = 64;
constexpr int N = B * NN;          // 51200
constexpr int E = B * NN * DEG;    // 3276800
constexpr int EPG = NN * DEG;      // 25600 edges per graph
constexpr int SPL = 4;             // edge splits per graph
constexpr int EPS = EPG / SPL;     // 6400 edges per split-block

__device__ __forceinline__ float lrelu(float t) { return t > 0.f ? t : 0.01f * t; }

// K1: h0 = leaky_relu(x @ fc1_w.T + fc1_b)   [128,400]
__global__ void k_h0(const float* __restrict__ x, const float* __restrict__ fc1w,
                     const float* __restrict__ fc1b, float* __restrict__ h0g) {
    int b  = blockIdx.x >> 1;
    int nb = (blockIdx.x & 1) * 200;
    __shared__ float xs[FEAT];
    if (threadIdx.x < FEAT) xs[threadIdx.x] = x[b * FEAT + threadIdx.x];
    __syncthreads();
    if (threadIdx.x < 200) {
        int n = nb + threadIdx.x;
        const float4* w4 = reinterpret_cast<const float4*>(fc1w + n * FEAT);
        float s = 0.f;
        #pragma unroll 4
        for (int k4 = 0; k4 < FEAT / 4; ++k4) {
            float4 p = w4[k4];
            const float* xk = xs + k4 * 4;
            s += p.x * xk[0] + p.y * xk[1] + p.z * xk[2] + p.w * xk[3];
        }
        h0g[b * NN + n] = lrelu(s + fc1b[n]);
    }
}

// K2: per-split destination histogram.  grid 512 (b,sp), block 256
__global__ void k_hist(const int* __restrict__ ei, u32* __restrict__ cntp) {
    int b = blockIdx.x >> 2, sp = blockIdx.x & 3;
    __shared__ u32 hist[NN];
    for (int i = threadIdx.x; i < NN; i += 256) hist[i] = 0u;
    __syncthreads();
    int boff = b * NN;
    int ebase = b * EPG + sp * EPS;
    for (int e = ebase + (int)threadIdx.x; e < ebase + EPS; e += 256)
        atomicAdd(&hist[ei[E + e] - boff], 1u);
    __syncthreads();
    for (int i = threadIdx.x; i < NN; i += 256)
        cntp[sp * N + boff + i] = hist[i];
}

// K3: scatter into dst-sorted CSR order.  grid 512 (b,sp), block 512
// Each block recomputes the graph-wide exclusive scan of total counts, offsets
// its cursors by earlier splits' per-node counts, then claims slots via LDS u32
// atomics. sp==0 block also persists offg (u32) and cntg (float).
__global__ void __launch_bounds__(512, 2)
k_scatter(const int* __restrict__ ei, const float* __restrict__ ea,
          const u32* __restrict__ cntp, u32* __restrict__ offg,
          float* __restrict__ cntg, uint2* __restrict__ sortedq) {
    int b = blockIdx.x >> 2, sp = blockIdx.x & 3;
    int boff = b * NN;
    __shared__ u32 cursor[NN];
    __shared__ u32 wsum[8];

    int t = (int)threadIdx.x;
    int lane = t & 63, wave = t >> 6;
    u32 c0 = 0, c1 = 0, c2 = 0, c3 = 0, tot = 0;
    if (t < NN) {
        c0 = cntp[0 * N + boff + t];
        c1 = cntp[1 * N + boff + t];
        c2 = cntp[2 * N + boff + t];
        c3 = cntp[3 * N + boff + t];
        tot = c0 + c1 + c2 + c3;
    }
    // wave-inclusive scan of tot
    u32 x = tot;
    #pragma unroll
    for (int d = 1; d < 64; d <<= 1) {
        u32 o = __shfl_up(x, d);
        if (lane >= d) x += o;
    }
    u32 wtot = __shfl(x, 63);
    if (lane == 0) wsum[wave] = wtot;
    __syncthreads();
    u32 wpre = 0;
    for (int w2 = 0; w2 < wave; ++w2) wpre += wsum[w2];
    if (t < NN) {
        u32 off_n = x + wpre - tot;                 // exclusive scan
        u32 base = off_n;
        if (sp > 0) base += c0;
        if (sp > 1) base += c1;
        if (sp > 2) base += c2;
        cursor[t] = base;
        if (sp == 0) {
            offg[boff + t] = off_n;
            cntg[boff + t] = (float)tot;
        }
    }
    __syncthreads();

    int ebase = b * EPG + sp * EPS;
    size_t goff = (size_t)b * EPG;
    for (int e = ebase + t; e < ebase + EPS; e += 512) {
        int s = ei[e] - boff;
        int d = ei[E + e] - boff;
        float w = ea[e];
        u32 slot = atomicAdd(&cursor[d], 1u);
        sortedq[goff + slot] = make_uint2((u32)s, __float_as_uint(w));
    }
}

// K4: conv1 gather + h1 update fused.  grid 256 (b,half), block 256
__global__ void k_g1h1(const uint2* __restrict__ sortedq, const u32* __restrict__ offg,
                       const float* __restrict__ cntg, const float* __restrict__ h0g,
                       const float* __restrict__ Wr1, const float* __restrict__ br1,
                       const float* __restrict__ Wo1, float* __restrict__ h1g) {
    int b = blockIdx.x >> 1, half = blockIdx.x & 1;
    int boff = b * NN;
    __shared__ float h0s[NN];
    for (int i = threadIdx.x; i < NN; i += 256) h0s[i] = h0g[boff + i];
    __syncthreads();
    int tn = (int)threadIdx.x;
    if (tn < 200) {
        int n = half * 200 + tn;
        u32 off = offg[boff + n];
        float c = cntg[boff + n];
        int cnt = (int)c;
        const uint2* q = sortedq + (size_t)b * EPG + off;
        float a = 0.f;
        for (int i = 0; i < cnt; ++i) {
            uint2 p = q[i];
            a += __uint_as_float(p.y) * h0s[p.x];
        }
        a /= fmaxf(c, 1.f);
        float h0 = h0s[n];
        float v[8];
        #pragma unroll
        for (int k = 0; k < 8; ++k)
            v[k] = lrelu(a * Wr1[k] + br1[k] + h0 * Wo1[k]);
        float4* o = reinterpret_cast<float4*>(h1g + (size_t)(boff + n) * 8);
        o[0] = make_float4(v[0], v[1], v[2], v[3]);
        o[1] = make_float4(v[4], v[5], v[6], v[7]);
    }
}

// K5: conv2 gather (8 ch), writes mean-divided agg2.  grid 256 (b,half), block 256
__global__ void k_g2(const uint2* __restrict__ sortedq, const u32* __restrict__ offg,
                     const float* __restrict__ cntg, const float* __restrict__ h1g,
                     float* __restrict__ agg2m) {
    int b = blockIdx.x >> 1, half = blockIdx.x & 1;
    int boff = b * NN;
    __shared__ alignas(16) float h1s[NN * 8];
    {
        const float4* src = reinterpret_cast<const float4*>(h1g + (size_t)boff * 8);
        float4* dst = reinterpret_cast<float4*>(h1s);
        for (int i = threadIdx.x; i < NN * 2; i += 256) dst[i] = src[i];
    }
    __syncthreads();
    int tn = (int)threadIdx.x;
    if (tn < 200) {
        int n = half * 200 + tn;
        u32 off = offg[boff + n];
        float c = cntg[boff + n];
        int cnt = (int)c;
        const uint2* q = sortedq + (size_t)b * EPG + off;
        float acc[8];
        #pragma unroll
        for (int k = 0; k < 8; ++k) acc[k] = 0.f;
        for (int i = 0; i < cnt; ++i) {
            uint2 p = q[i];
            float w = __uint_as_float(p.y);
            const float4* hv = reinterpret_cast<const float4*>(h1s + p.x * 8);
            float4 v0 = hv[0], v1 = hv[1];
            acc[0] += w * v0.x; acc[1] += w * v0.y; acc[2] += w * v0.z; acc[3] += w * v0.w;
            acc[4] += w * v1.x; acc[5] += w * v1.y; acc[6] += w * v1.z; acc[7] += w * v1.w;
        }
        float inv = 1.f / fmaxf(c, 1.f);
        float4* o = reinterpret_cast<float4*>(agg2m + (size_t)(boff + n) * 8);
        o[0] = make_float4(acc[0] * inv, acc[1] * inv, acc[2] * inv, acc[3] * inv);
        o[1] = make_float4(acc[4] * inv, acc[5] * inv, acc[6] * inv, acc[7] * inv);
    }
}

// K6: out[b,i,j] = sigmoid(0.5*(z_i.m_j + z_j.m_i + bb[i] + bb[j]))
// grid 512 (128 graphs x 4 row-blocks of 100), block 512
__global__ void __launch_bounds__(512, 4)
k_out(const float* __restrict__ h1g, const float* __restrict__ agg2m,
      const float* __restrict__ Wr2, const float* __restrict__ br2,
      const float* __restrict__ Wo2, float* __restrict__ out) {
    int b = blockIdx.x >> 2, rb = blockIdx.x & 3;
    __shared__ alignas(16) float Zt[16 * NN];
    __shared__ alignas(16) float Mt[16 * NN];
    __shared__ float bbs[NN];

    int j = threadIdx.x;
    if (j < NN) {
        int n = b * NN + j;
        const float4* av = reinterpret_cast<const float4*>(agg2m + (size_t)n * 8);
        float4 a0 = av[0], a1 = av[1];
        Zt[0 * NN + j] = a0.x; Zt[1 * NN + j] = a0.y;
        Zt[2 * NN + j] = a0.z; Zt[3 * NN + j] = a0.w;
        Zt[4 * NN + j] = a1.x; Zt[5 * NN + j] = a1.y;
        Zt[6 * NN + j] = a1.z; Zt[7 * NN + j] = a1.w;
        const float4* hv = reinterpret_cast<const float4*>(h1g + (size_t)n * 8);
        float4 h0v = hv[0], h1v = hv[1];
        Zt[ 8 * NN + j] = h0v.x; Zt[ 9 * NN + j] = h0v.y;
        Zt[10 * NN + j] = h0v.z; Zt[11 * NN + j] = h0v.w;
        Zt[12 * NN + j] = h1v.x; Zt[13 * NN + j] = h1v.y;
        Zt[14 * NN + j] = h1v.z; Zt[15 * NN + j] = h1v.w;
        const float* wr = Wr2 + j * 8;
        const float* wo = Wo2 + j * 8;
        #pragma unroll
        for (int k = 0; k < 8; ++k) {
            Mt[k * NN + j]       = wr[k];
            Mt[(8 + k) * NN + j] = wo[k];
        }
        bbs[j] = br2[j];
    }
    __syncthreads();

    for (int t = threadIdx.x; t < 25 * 50; t += 512) {
        int ti = t % 25, tj = t / 25;
        int i0 = rb * 100 + ti * 4;
        int j0 = tj * 8;
        float acc[4][8];
        #pragma unroll
        for (int r = 0; r < 4; ++r)
            #pragma unroll
            for (int cc = 0; cc < 8; ++cc) acc[r][cc] = 0.f;

        #pragma unroll
        for (int k = 0; k < 16; ++k) {
            const float* zr = Zt + k * NN;
            const float* mr = Mt + k * NN;
            float4 az  = *reinterpret_cast<const float4*>(zr + i0);
            float4 am  = *reinterpret_cast<const float4*>(mr + i0);
            float4 bz0 = *reinterpret_cast<const float4*>(zr + j0);
            float4 bz1 = *reinterpret_cast<const float4*>(zr + j0 + 4);
            float4 bm0 = *reinterpret_cast<const float4*>(mr + j0);
            float4 bm1 = *reinterpret_cast<const float4*>(mr + j0 + 4);
            float ar[4]  = {az.x, az.y, az.z, az.w};
            float amr[4] = {am.x, am.y, am.z, am.w};
            float bzv[8] = {bz0.x, bz0.y, bz0.z, bz0.w, bz1.x, bz1.y, bz1.z, bz1.w};
            float bmv[8] = {bm0.x, bm0.y, bm0.z, bm0.w, bm1.x, bm1.y, bm1.z, bm1.w};
            #pragma unroll
            for (int r = 0; r < 4; ++r)
                #pragma unroll
                for (int cc = 0; cc < 8; ++cc)
                    acc[r][cc] += ar[r] * bmv[cc] + amr[r] * bzv[cc];
        }

        float bi[4], bj[8];
        #pragma unroll
        for (int r = 0; r < 4; ++r) bi[r] = bbs[i0 + r];
        #pragma unroll
        for (int cc = 0; cc < 8; ++cc) bj[cc] = bbs[j0 + cc];

        size_t obase = (size_t)b * NN * NN;
        #pragma unroll
        for (int r = 0; r < 4; ++r) {
            float vout[8];
            #pragma unroll
            for (int cc = 0; cc < 8; ++cc) {
                float xv = 0.5f * (acc[r][cc] + bi[r] + bj[cc]);
                vout[cc] = 1.f / (1.f + __expf(-xv));
            }
            float* op = out + obase + (size_t)(i0 + r) * NN + j0;
            *reinterpret_cast<float4*>(op)     = make_float4(vout[0], vout[1], vout[2], vout[3]);
            *reinterpret_cast<float4*>(op + 4) = make_float4(vout[4], vout[5], vout[6], vout[7]);
        }
    }
}

extern "C" void kernel_launch(void* const* d_in, const int* in_sizes, int n_in,
                              void* d_out, int out_size, void* d_ws, size_t ws_size,
                              hipStream_t stream) {
    const float* x    = (const float*)d_in[0];
    const int*   ei   = (const int*)d_in[1];
    const float* ea   = (const float*)d_in[2];
    const float* fc1w = (const float*)d_in[3];
    const float* fc1b = (const float*)d_in[4];
    const float* Wr1  = (const float*)d_in[5];
    const float* br1  = (const float*)d_in[6];
    const float* Wo1  = (const float*)d_in[7];
    const float* Wr2  = (const float*)d_in[8];
    const float* br2  = (const float*)d_in[9];
    const float* Wo2  = (const float*)d_in[10];
    float* out = (float*)d_out;

    float* ws     = (float*)d_ws;
    float* h0g    = ws;                              // N
    float* cntg   = ws + N;                          // N
    float* h1g    = ws + 2 * N;                      // 8N
    float* agg2m  = ws + 10 * N;                     // 8N
    u32*   offg   = (u32*)(ws + 18 * N);             // N
    u32*   cntp   = (u32*)(ws + 19 * N);             // 4N
    uint2* sortedq = (uint2*)(ws + 23 * N);          // E uint2 = 26.2 MB (total ~30.9 MB)

    hipLaunchKernelGGL(k_h0,      dim3(256), dim3(256), 0, stream, x, fc1w, fc1b, h0g);
    hipLaunchKernelGGL(k_hist,    dim3(512), dim3(256), 0, stream, ei, cntp);
    hipLaunchKernelGGL(k_scatter, dim3(512), dim3(512), 0, stream, ei, ea, cntp, offg, cntg, sortedq);
    hipLaunchKernelGGL(k_g1h1,    dim3(256), dim3(256), 0, stream, sortedq, offg, cntg, h0g, Wr1, br1, Wo1, h1g);
    hipLaunchKernelGGL(k_g2,      dim3(256), dim3(256), 0, stream, sortedq, offg, cntg, h1g, agg2m);
    hipLaunchKernelGGL(k_out,     dim3(512), dim3(512), 0, stream, h1g, agg2m, Wr2, br2, Wo2, out);
}

// Round 5
// 93.538 us; speedup vs baseline: 2.3967x; 1.1480x over previous
//
#include <hip/hip_runtime.h>

typedef unsigned int u32;

constexpr int B = 128, NN = 400, FEAT = 256, DEG = 64;
constexpr int N = B * NN;          // 51200
constexpr int E = B * NN * DEG;    // 3276800
constexpr int EPG = NN * DEG;      // 25600 edges per graph
constexpr int SPL = 4;             // edge splits per graph
constexpr int EPS = EPG / SPL;     // 6400 edges per split-block

__device__ __forceinline__ float lrelu(float t) { return t > 0.f ? t : 0.01f * t; }

// K1: h0 = leaky_relu(x @ fc1_w.T + fc1_b)   [128,400]
__global__ void k_h0(const float* __restrict__ x, const float* __restrict__ fc1w,
                     const float* __restrict__ fc1b, float* __restrict__ h0g) {
    int b  = blockIdx.x >> 1;
    int nb = (blockIdx.x & 1) * 200;
    __shared__ float xs[FEAT];
    if (threadIdx.x < FEAT) xs[threadIdx.x] = x[b * FEAT + threadIdx.x];
    __syncthreads();
    if (threadIdx.x < 200) {
        int n = nb + threadIdx.x;
        const float4* w4 = reinterpret_cast<const float4*>(fc1w + n * FEAT);
        float s = 0.f;
        #pragma unroll 4
        for (int k4 = 0; k4 < FEAT / 4; ++k4) {
            float4 p = w4[k4];
            const float* xk = xs + k4 * 4;
            s += p.x * xk[0] + p.y * xk[1] + p.z * xk[2] + p.w * xk[3];
        }
        h0g[b * NN + n] = lrelu(s + fc1b[n]);
    }
}

// K2: fused hist + scan + LDS counting-sort + coalesced flush.
// Per-split CSR: sortedq[b][sp][0..EPS) sorted by local dst; qoff/qcnt per (sp,b,n).
// grid 512 (b,sp), block 512
__global__ void __launch_bounds__(512, 2)
k_sort(const int* __restrict__ ei, const float* __restrict__ ea,
       uint2* __restrict__ sortedq, u32* __restrict__ qoff, u32* __restrict__ qcnt) {
    int b = blockIdx.x >> 2, sp = blockIdx.x & 3;
    int boff = b * NN;
    __shared__ u32 hist[NN];                 // histogram, then cursor
    __shared__ u32 wsum[8];
    __shared__ alignas(16) uint2 q[EPS];     // 51.2 KB staging

    int t = (int)threadIdx.x;
    for (int i = t; i < NN; i += 512) hist[i] = 0u;
    __syncthreads();

    int ebase = b * EPG + sp * EPS;
    // pass 1: histogram of local dst
    for (int e = ebase + t; e < ebase + EPS; e += 512)
        atomicAdd(&hist[ei[E + e] - boff], 1u);
    __syncthreads();

    // exclusive scan of hist[0..NN)
    int lane = t & 63, wave = t >> 6;
    u32 c = (t < NN) ? hist[t] : 0u;
    u32 x = c;
    #pragma unroll
    for (int d = 1; d < 64; d <<= 1) {
        u32 o = __shfl_up(x, d);
        if (lane >= d) x += o;
    }
    u32 wtot = __shfl(x, 63);
    if (lane == 0) wsum[wave] = wtot;
    __syncthreads();
    u32 wpre = 0;
    for (int w2 = 0; w2 < wave; ++w2) wpre += wsum[w2];
    __syncthreads();            // everyone done reading hist before overwrite
    if (t < NN) {
        u32 off = x + wpre - c;                  // exclusive scan
        hist[t] = off;                           // becomes cursor
        qoff[sp * N + boff + t] = off;
        qcnt[sp * N + boff + t] = c;
    }
    __syncthreads();

    // pass 2: place edges into LDS queue
    for (int e = ebase + t; e < ebase + EPS; e += 512) {
        int s = ei[e] - boff;
        int d = ei[E + e] - boff;
        float w = ea[e];
        u32 slot = atomicAdd(&hist[d], 1u);
        q[slot] = make_uint2((u32)s, __float_as_uint(w));
    }
    __syncthreads();

    // coalesced flush (uint4 = 2 edges per store)
    uint4* dst4 = reinterpret_cast<uint4*>(sortedq + (size_t)b * EPG + sp * EPS);
    const uint4* src4 = reinterpret_cast<const uint4*>(q);
    for (int i = t; i < EPS / 2; i += 512) dst4[i] = src4[i];
}

// K3: conv1 gather + h1 update fused.  grid 256 (b,half), block 256
__global__ void k_g1h1(const uint2* __restrict__ sortedq, const u32* __restrict__ qoff,
                       const u32* __restrict__ qcnt, const float* __restrict__ h0g,
                       const float* __restrict__ Wr1, const float* __restrict__ br1,
                       const float* __restrict__ Wo1, float* __restrict__ h1g) {
    int b = blockIdx.x >> 1, half = blockIdx.x & 1;
    int boff = b * NN;
    __shared__ float h0s[NN];
    for (int i = threadIdx.x; i < NN; i += 256) h0s[i] = h0g[boff + i];
    __syncthreads();
    int tn = (int)threadIdx.x;
    if (tn < 200) {
        int n = half * 200 + tn;
        float a = 0.f;
        u32 ct = 0;
        #pragma unroll
        for (int sp = 0; sp < SPL; ++sp) {
            u32 off = qoff[sp * N + boff + n];
            u32 c   = qcnt[sp * N + boff + n];
            ct += c;
            const uint2* q = sortedq + (size_t)b * EPG + sp * EPS + off;
            for (u32 i = 0; i < c; ++i) {
                uint2 p = q[i];
                a += __uint_as_float(p.y) * h0s[p.x];
            }
        }
        float cf = (float)ct;
        a /= fmaxf(cf, 1.f);
        float h0 = h0s[n];
        float v[8];
        #pragma unroll
        for (int k = 0; k < 8; ++k)
            v[k] = lrelu(a * Wr1[k] + br1[k] + h0 * Wo1[k]);
        float4* o = reinterpret_cast<float4*>(h1g + (size_t)(boff + n) * 8);
        o[0] = make_float4(v[0], v[1], v[2], v[3]);
        o[1] = make_float4(v[4], v[5], v[6], v[7]);
    }
}

// K4: conv2 gather (8 ch), writes mean-divided agg2.  grid 256 (b,half), block 256
__global__ void k_g2(const uint2* __restrict__ sortedq, const u32* __restrict__ qoff,
                     const u32* __restrict__ qcnt, const float* __restrict__ h1g,
                     float* __restrict__ agg2m) {
    int b = blockIdx.x >> 1, half = blockIdx.x & 1;
    int boff = b * NN;
    __shared__ alignas(16) float h1s[NN * 8];
    {
        const float4* src = reinterpret_cast<const float4*>(h1g + (size_t)boff * 8);
        float4* dst = reinterpret_cast<float4*>(h1s);
        for (int i = threadIdx.x; i < NN * 2; i += 256) dst[i] = src[i];
    }
    __syncthreads();
    int tn = (int)threadIdx.x;
    if (tn < 200) {
        int n = half * 200 + tn;
        float acc[8];
        #pragma unroll
        for (int k = 0; k < 8; ++k) acc[k] = 0.f;
        u32 ct = 0;
        #pragma unroll
        for (int sp = 0; sp < SPL; ++sp) {
            u32 off = qoff[sp * N + boff + n];
            u32 c   = qcnt[sp * N + boff + n];
            ct += c;
            const uint2* q = sortedq + (size_t)b * EPG + sp * EPS + off;
            for (u32 i = 0; i < c; ++i) {
                uint2 p = q[i];
                float w = __uint_as_float(p.y);
                const float4* hv = reinterpret_cast<const float4*>(h1s + p.x * 8);
                float4 v0 = hv[0], v1 = hv[1];
                acc[0] += w * v0.x; acc[1] += w * v0.y; acc[2] += w * v0.z; acc[3] += w * v0.w;
                acc[4] += w * v1.x; acc[5] += w * v1.y; acc[6] += w * v1.z; acc[7] += w * v1.w;
            }
        }
        float inv = 1.f / fmaxf((float)ct, 1.f);
        float4* o = reinterpret_cast<float4*>(agg2m + (size_t)(boff + n) * 8);
        o[0] = make_float4(acc[0] * inv, acc[1] * inv, acc[2] * inv, acc[3] * inv);
        o[1] = make_float4(acc[4] * inv, acc[5] * inv, acc[6] * inv, acc[7] * inv);
    }
}

// K5: out[b,i,j] = sigmoid(0.5*(z_i.m_j + z_j.m_i + bb[i] + bb[j]))
// grid 512 (128 graphs x 4 row-blocks of 100), block 512
__global__ void __launch_bounds__(512, 4)
k_out(const float* __restrict__ h1g, const float* __restrict__ agg2m,
      const float* __restrict__ Wr2, const float* __restrict__ br2,
      const float* __restrict__ Wo2, float* __restrict__ out) {
    int b = blockIdx.x >> 2, rb = blockIdx.x & 3;
    __shared__ alignas(16) float Zt[16 * NN];
    __shared__ alignas(16) float Mt[16 * NN];
    __shared__ float bbs[NN];

    int j = threadIdx.x;
    if (j < NN) {
        int n = b * NN + j;
        const float4* av = reinterpret_cast<const float4*>(agg2m + (size_t)n * 8);
        float4 a0 = av[0], a1 = av[1];
        Zt[0 * NN + j] = a0.x; Zt[1 * NN + j] = a0.y;
        Zt[2 * NN + j] = a0.z; Zt[3 * NN + j] = a0.w;
        Zt[4 * NN + j] = a1.x; Zt[5 * NN + j] = a1.y;
        Zt[6 * NN + j] = a1.z; Zt[7 * NN + j] = a1.w;
        const float4* hv = reinterpret_cast<const float4*>(h1g + (size_t)n * 8);
        float4 h0v = hv[0], h1v = hv[1];
        Zt[ 8 * NN + j] = h0v.x; Zt[ 9 * NN + j] = h0v.y;
        Zt[10 * NN + j] = h0v.z; Zt[11 * NN + j] = h0v.w;
        Zt[12 * NN + j] = h1v.x; Zt[13 * NN + j] = h1v.y;
        Zt[14 * NN + j] = h1v.z; Zt[15 * NN + j] = h1v.w;
        const float* wr = Wr2 + j * 8;
        const float* wo = Wo2 + j * 8;
        #pragma unroll
        for (int k = 0; k < 8; ++k) {
            Mt[k * NN + j]       = wr[k];
            Mt[(8 + k) * NN + j] = wo[k];
        }
        bbs[j] = br2[j];
    }
    __syncthreads();

    for (int t = threadIdx.x; t < 25 * 50; t += 512) {
        int ti = t % 25, tj = t / 25;
        int i0 = rb * 100 + ti * 4;
        int j0 = tj * 8;
        float acc[4][8];
        #pragma unroll
        for (int r = 0; r < 4; ++r)
            #pragma unroll
            for (int cc = 0; cc < 8; ++cc) acc[r][cc] = 0.f;

        #pragma unroll
        for (int k = 0; k < 16; ++k) {
            const float* zr = Zt + k * NN;
            const float* mr = Mt + k * NN;
            float4 az  = *reinterpret_cast<const float4*>(zr + i0);
            float4 am  = *reinterpret_cast<const float4*>(mr + i0);
            float4 bz0 = *reinterpret_cast<const float4*>(zr + j0);
            float4 bz1 = *reinterpret_cast<const float4*>(zr + j0 + 4);
            float4 bm0 = *reinterpret_cast<const float4*>(mr + j0);
            float4 bm1 = *reinterpret_cast<const float4*>(mr + j0 + 4);
            float ar[4]  = {az.x, az.y, az.z, az.w};
            float amr[4] = {am.x, am.y, am.z, am.w};
            float bzv[8] = {bz0.x, bz0.y, bz0.z, bz0.w, bz1.x, bz1.y, bz1.z, bz1.w};
            float bmv[8] = {bm0.x, bm0.y, bm0.z, bm0.w, bm1.x, bm1.y, bm1.z, bm1.w};
            #pragma unroll
            for (int r = 0; r < 4; ++r)
                #pragma unroll
                for (int cc = 0; cc < 8; ++cc)
                    acc[r][cc] += ar[r] * bmv[cc] + amr[r] * bzv[cc];
        }

        float bi[4], bj[8];
        #pragma unroll
        for (int r = 0; r < 4; ++r) bi[r] = bbs[i0 + r];
        #pragma unroll
        for (int cc = 0; cc < 8; ++cc) bj[cc] = bbs[j0 + cc];

        size_t obase = (size_t)b * NN * NN;
        #pragma unroll
        for (int r = 0; r < 4; ++r) {
            float vout[8];
            #pragma unroll
            for (int cc = 0; cc < 8; ++cc) {
                float xv = 0.5f * (acc[r][cc] + bi[r] + bj[cc]);
                vout[cc] = 1.f / (1.f + __expf(-xv));
            }
            float* op = out + obase + (size_t)(i0 + r) * NN + j0;
            *reinterpret_cast<float4*>(op)     = make_float4(vout[0], vout[1], vout[2], vout[3]);
            *reinterpret_cast<float4*>(op + 4) = make_float4(vout[4], vout[5], vout[6], vout[7]);
        }
    }
}

extern "C" void kernel_launch(void* const* d_in, const int* in_sizes, int n_in,
                              void* d_out, int out_size, void* d_ws, size_t ws_size,
                              hipStream_t stream) {
    const float* x    = (const float*)d_in[0];
    const int*   ei   = (const int*)d_in[1];
    const float* ea   = (const float*)d_in[2];
    const float* fc1w = (const float*)d_in[3];
    const float* fc1b = (const float*)d_in[4];
    const float* Wr1  = (const float*)d_in[5];
    const float* br1  = (const float*)d_in[6];
    const float* Wo1  = (const float*)d_in[7];
    const float* Wr2  = (const float*)d_in[8];
    const float* br2  = (const float*)d_in[9];
    const float* Wo2  = (const float*)d_in[10];
    float* out = (float*)d_out;

    float* ws      = (float*)d_ws;
    float* h0g     = ws;                       // N
    float* h1g     = ws + N;                   // 8N
    float* agg2m   = ws + 9 * N;               // 8N
    u32*   qoff    = (u32*)(ws + 17 * N);      // 4N
    u32*   qcnt    = (u32*)(ws + 21 * N);      // 4N
    uint2* sortedq = (uint2*)(ws + 25 * N);    // E uint2 = 26.2 MB (total ~31.3 MB)

    hipLaunchKernelGGL(k_h0,   dim3(256), dim3(256), 0, stream, x, fc1w, fc1b, h0g);
    hipLaunchKernelGGL(k_sort, dim3(512), dim3(512), 0, stream, ei, ea, sortedq, qoff, qcnt);
    hipLaunchKernelGGL(k_g1h1, dim3(256), dim3(256), 0, stream, sortedq, qoff, qcnt, h0g, Wr1, br1, Wo1, h1g);
    hipLaunchKernelGGL(k_g2,   dim3(256), dim3(256), 0, stream, sortedq, qoff, qcnt, h1g, agg2m);
    hipLaunchKernelGGL(k_out,  dim3(512), dim3(512), 0, stream, h1g, agg2m, Wr2, br2, Wo2, out);
}

// Round 6
// 74.239 us; speedup vs baseline: 3.0197x; 1.2600x over previous
//
#include <hip/hip_runtime.h>

typedef unsigned int u32;

constexpr int B = 128, NN = 400, FEAT = 256, DEG = 64;
constexpr int N = B * NN;          // 51200
constexpr int E = B * NN * DEG;    // 3276800
constexpr int EPG = NN * DEG;      // 25600 edges per graph
constexpr int SPL = 4;             // edge splits per graph
constexpr int EPS = EPG / SPL;     // 6400 edges per split-block
constexpr int EPT = 13;            // ceil(EPS / 512) staged edges per thread

__device__ __forceinline__ float lrelu(float t) { return t > 0.f ? t : 0.01f * t; }

// K1: h0 = leaky_relu(x @ fc1_w.T + fc1_b)   [128,400]
__global__ void k_h0(const float* __restrict__ x, const float* __restrict__ fc1w,
                     const float* __restrict__ fc1b, float* __restrict__ h0g) {
    int b  = blockIdx.x >> 1;
    int nb = (blockIdx.x & 1) * 200;
    __shared__ float xs[FEAT];
    if (threadIdx.x < FEAT) xs[threadIdx.x] = x[b * FEAT + threadIdx.x];
    __syncthreads();
    if (threadIdx.x < 200) {
        int n = nb + threadIdx.x;
        const float4* w4 = reinterpret_cast<const float4*>(fc1w + n * FEAT);
        float s = 0.f;
        #pragma unroll 4
        for (int k4 = 0; k4 < FEAT / 4; ++k4) {
            float4 p = w4[k4];
            const float* xk = xs + k4 * 4;
            s += p.x * xk[0] + p.y * xk[1] + p.z * xk[2] + p.w * xk[3];
        }
        h0g[b * NN + n] = lrelu(s + fc1b[n]);
    }
}

// K2: fused reg-staged hist + scan + LDS counting-sort + coalesced flush +
//     conv1 partial gather (from LDS queue, h0 staged in LDS).
// Queue entry: (bf16(w) << 16) | src  -> 4 B/edge.
// grid 512 (b,sp), block 512
__global__ void __launch_bounds__(512, 2)
k_sort(const int* __restrict__ ei, const float* __restrict__ ea,
       const float* __restrict__ h0g,
       u32* __restrict__ sortedq, u32* __restrict__ qoff, u32* __restrict__ qcnt,
       float* __restrict__ agg1p) {
    int b = blockIdx.x >> 2, sp = blockIdx.x & 3;
    int boff = b * NN;
    __shared__ u32 hist[NN];                 // histogram, then cursor
    __shared__ float h0s[NN];
    __shared__ u32 wsum[8];
    __shared__ u32 q[EPS];                   // 25.6 KB packed staging

    int t = (int)threadIdx.x;
    if (t < NN) { hist[t] = 0u; h0s[t] = h0g[boff + t]; }

    // register-stage this thread's edges (single pass over ei/ea)
    int ebase = b * EPG + sp * EPS;
    int de[EPT];
    u32 pk[EPT];
    #pragma unroll
    for (int i = 0; i < EPT; ++i) {
        int idx = t + i * 512;
        de[i] = -1; pk[i] = 0u;
        if (idx < EPS) {
            int e = ebase + idx;
            int s = ei[e] - boff;
            de[i] = ei[E + e] - boff;
            u32 uw = __float_as_uint(ea[e]);
            u32 r = uw + 0x7fffu + ((uw >> 16) & 1u);   // rne to bf16
            pk[i] = (r & 0xffff0000u) | (u32)s;
        }
    }
    __syncthreads();

    // histogram from registers
    #pragma unroll
    for (int i = 0; i < EPT; ++i)
        if (de[i] >= 0) atomicAdd(&hist[de[i]], 1u);
    __syncthreads();

    // exclusive scan of hist[0..NN)
    int lane = t & 63, wave = t >> 6;
    u32 c = (t < NN) ? hist[t] : 0u;
    u32 x = c;
    #pragma unroll
    for (int d = 1; d < 64; d <<= 1) {
        u32 o = __shfl_up(x, d);
        if (lane >= d) x += o;
    }
    u32 wtot = __shfl(x, 63);
    if (lane == 0) wsum[wave] = wtot;
    __syncthreads();
    u32 wpre = 0;
    for (int w2 = 0; w2 < wave; ++w2) wpre += wsum[w2];
    u32 off = x + wpre - c;                  // exclusive scan (thread t owns node t)
    __syncthreads();                         // all hist reads done before overwrite
    if (t < NN) {
        hist[t] = off;                       // becomes cursor
        qoff[sp * N + boff + t] = off;
        qcnt[sp * N + boff + t] = c;
    }
    __syncthreads();

    // place edges into LDS queue from registers
    #pragma unroll
    for (int i = 0; i < EPT; ++i)
        if (de[i] >= 0) {
            u32 slot = atomicAdd(&hist[de[i]], 1u);
            q[slot] = pk[i];
        }
    __syncthreads();

    // coalesced flush (uint4 = 4 edges per store)
    uint4* dst4 = reinterpret_cast<uint4*>(sortedq + (size_t)b * EPG + sp * EPS);
    const uint4* src4 = reinterpret_cast<const uint4*>(q);
    for (int i = t; i < EPS / 4; i += 512) dst4[i] = src4[i];

    // conv1 partial gather from LDS queue (off, c already in this thread's regs)
    if (t < NN) {
        float a = 0.f;
        for (u32 i = 0; i < c; ++i) {
            u32 p = q[off + i];
            a += __uint_as_float(p & 0xffff0000u) * h0s[p & 0xffffu];
        }
        agg1p[sp * N + boff + t] = a;
    }
}

// K3: h1 compute (dup x4) + conv2 per-split gather -> agg2p partials.
// grid 512 (b,sp), block 512
__global__ void __launch_bounds__(512, 2)
k_g2(const u32* __restrict__ sortedq, const u32* __restrict__ qoff,
     const u32* __restrict__ qcnt, const float* __restrict__ agg1p,
     const float* __restrict__ h0g,
     const float* __restrict__ Wr1, const float* __restrict__ br1,
     const float* __restrict__ Wo1,
     float* __restrict__ h1g, float* __restrict__ cntg, float* __restrict__ agg2p) {
    int b = blockIdx.x >> 2, sp = blockIdx.x & 3;
    int boff = b * NN;
    __shared__ alignas(16) float h1s[NN * 8];   // 12.8 KB

    int t = (int)threadIdx.x;
    u32 myoff = 0, myc = 0;
    if (t < NN) {
        float a = 0.f; u32 ct = 0;
        #pragma unroll
        for (int s2 = 0; s2 < SPL; ++s2) {
            a  += agg1p[s2 * N + boff + t];
            u32 cc = qcnt[s2 * N + boff + t];
            ct += cc;
            if (s2 == sp) myc = cc;
        }
        myoff = qoff[sp * N + boff + t];
        float cf = (float)ct;
        a *= __builtin_amdgcn_rcpf(fmaxf(cf, 1.f));
        float h0 = h0g[boff + t];
        float v[8];
        #pragma unroll
        for (int k = 0; k < 8; ++k)
            v[k] = lrelu(a * Wr1[k] + br1[k] + h0 * Wo1[k]);
        float4* hl = reinterpret_cast<float4*>(h1s + t * 8);
        hl[0] = make_float4(v[0], v[1], v[2], v[3]);
        hl[1] = make_float4(v[4], v[5], v[6], v[7]);
        if (sp == 0) {
            float4* o = reinterpret_cast<float4*>(h1g + (size_t)(boff + t) * 8);
            o[0] = hl[0]; o[1] = hl[1];
            cntg[boff + t] = cf;
        }
    }
    __syncthreads();

    if (t < NN) {
        const u32* qp = sortedq + (size_t)b * EPG + sp * EPS + myoff;
        float acc[8];
        #pragma unroll
        for (int k = 0; k < 8; ++k) acc[k] = 0.f;
        for (u32 i = 0; i < myc; ++i) {
            u32 p = qp[i];
            float w = __uint_as_float(p & 0xffff0000u);
            const float4* hv = reinterpret_cast<const float4*>(h1s + (p & 0xffffu) * 8);
            float4 a0 = hv[0], a1 = hv[1];
            acc[0] += w * a0.x; acc[1] += w * a0.y; acc[2] += w * a0.z; acc[3] += w * a0.w;
            acc[4] += w * a1.x; acc[5] += w * a1.y; acc[6] += w * a1.z; acc[7] += w * a1.w;
        }
        float4* o = reinterpret_cast<float4*>(agg2p + ((size_t)sp * N + boff + t) * 8);
        o[0] = make_float4(acc[0], acc[1], acc[2], acc[3]);
        o[1] = make_float4(acc[4], acc[5], acc[6], acc[7]);
    }
}

// K4: out[b,i,j] = sigmoid(0.5*(z_i.m_j + z_j.m_i + bb[i] + bb[j]))
// z = [ (Σ_sp agg2p)/max(cnt,1) (8), h1 (8) ], m_j = [Wrel2[j,:], Wroot2[j,:]]
// grid 512 (128 graphs x 4 row-blocks of 100), block 512
__global__ void __launch_bounds__(512, 4)
k_out(const float* __restrict__ h1g, const float* __restrict__ agg2p,
      const float* __restrict__ cntg,
      const float* __restrict__ Wr2, const float* __restrict__ br2,
      const float* __restrict__ Wo2, float* __restrict__ out) {
    int b = blockIdx.x >> 2, rb = blockIdx.x & 3;
    __shared__ alignas(16) float Zt[16 * NN];
    __shared__ alignas(16) float Mt[16 * NN];
    __shared__ float bbs[NN];

    int j = threadIdx.x;
    if (j < NN) {
        int n = b * NN + j;
        float4 sA = make_float4(0, 0, 0, 0), sB = make_float4(0, 0, 0, 0);
        #pragma unroll
        for (int sp = 0; sp < SPL; ++sp) {
            const float4* ap = reinterpret_cast<const float4*>(agg2p + ((size_t)sp * N + n) * 8);
            float4 p0 = ap[0], p1 = ap[1];
            sA.x += p0.x; sA.y += p0.y; sA.z += p0.z; sA.w += p0.w;
            sB.x += p1.x; sB.y += p1.y; sB.z += p1.z; sB.w += p1.w;
        }
        float inv = __builtin_amdgcn_rcpf(fmaxf(cntg[n], 1.f));
        Zt[0 * NN + j] = sA.x * inv; Zt[1 * NN + j] = sA.y * inv;
        Zt[2 * NN + j] = sA.z * inv; Zt[3 * NN + j] = sA.w * inv;
        Zt[4 * NN + j] = sB.x * inv; Zt[5 * NN + j] = sB.y * inv;
        Zt[6 * NN + j] = sB.z * inv; Zt[7 * NN + j] = sB.w * inv;
        const float4* hv = reinterpret_cast<const float4*>(h1g + (size_t)n * 8);
        float4 h0v = hv[0], h1v = hv[1];
        Zt[ 8 * NN + j] = h0v.x; Zt[ 9 * NN + j] = h0v.y;
        Zt[10 * NN + j] = h0v.z; Zt[11 * NN + j] = h0v.w;
        Zt[12 * NN + j] = h1v.x; Zt[13 * NN + j] = h1v.y;
        Zt[14 * NN + j] = h1v.z; Zt[15 * NN + j] = h1v.w;
        const float* wr = Wr2 + j * 8;
        const float* wo = Wo2 + j * 8;
        #pragma unroll
        for (int k = 0; k < 8; ++k) {
            Mt[k * NN + j]       = wr[k];
            Mt[(8 + k) * NN + j] = wo[k];
        }
        bbs[j] = br2[j];
    }
    __syncthreads();

    for (int t = threadIdx.x; t < 25 * 50; t += 512) {
        int ti = t % 25, tj = t / 25;
        int i0 = rb * 100 + ti * 4;
        int j0 = tj * 8;
        float acc[4][8];
        #pragma unroll
        for (int r = 0; r < 4; ++r)
            #pragma unroll
            for (int cc = 0; cc < 8; ++cc) acc[r][cc] = 0.f;

        #pragma unroll
        for (int k = 0; k < 16; ++k) {
            const float* zr = Zt + k * NN;
            const float* mr = Mt + k * NN;
            float4 az  = *reinterpret_cast<const float4*>(zr + i0);
            float4 am  = *reinterpret_cast<const float4*>(mr + i0);
            float4 bz0 = *reinterpret_cast<const float4*>(zr + j0);
            float4 bz1 = *reinterpret_cast<const float4*>(zr + j0 + 4);
            float4 bm0 = *reinterpret_cast<const float4*>(mr + j0);
            float4 bm1 = *reinterpret_cast<const float4*>(mr + j0 + 4);
            float ar[4]  = {az.x, az.y, az.z, az.w};
            float amr[4] = {am.x, am.y, am.z, am.w};
            float bzv[8] = {bz0.x, bz0.y, bz0.z, bz0.w, bz1.x, bz1.y, bz1.z, bz1.w};
            float bmv[8] = {bm0.x, bm0.y, bm0.z, bm0.w, bm1.x, bm1.y, bm1.z, bm1.w};
            #pragma unroll
            for (int r = 0; r < 4; ++r)
                #pragma unroll
                for (int cc = 0; cc < 8; ++cc)
                    acc[r][cc] += ar[r] * bmv[cc] + amr[r] * bzv[cc];
        }

        float bi[4], bj[8];
        #pragma unroll
        for (int r = 0; r < 4; ++r) bi[r] = bbs[i0 + r];
        #pragma unroll
        for (int cc = 0; cc < 8; ++cc) bj[cc] = bbs[j0 + cc];

        size_t obase = (size_t)b * NN * NN;
        #pragma unroll
        for (int r = 0; r < 4; ++r) {
            float vout[8];
            #pragma unroll
            for (int cc = 0; cc < 8; ++cc) {
                float xv = 0.5f * (acc[r][cc] + bi[r] + bj[cc]);
                vout[cc] = __builtin_amdgcn_rcpf(1.f + __expf(-xv));
            }
            float* op = out + obase + (size_t)(i0 + r) * NN + j0;
            *reinterpret_cast<float4*>(op)     = make_float4(vout[0], vout[1], vout[2], vout[3]);
            *reinterpret_cast<float4*>(op + 4) = make_float4(vout[4], vout[5], vout[6], vout[7]);
        }
    }
}

extern "C" void kernel_launch(void* const* d_in, const int* in_sizes, int n_in,
                              void* d_out, int out_size, void* d_ws, size_t ws_size,
                              hipStream_t stream) {
    const float* x    = (const float*)d_in[0];
    const int*   ei   = (const int*)d_in[1];
    const float* ea   = (const float*)d_in[2];
    const float* fc1w = (const float*)d_in[3];
    const float* fc1b = (const float*)d_in[4];
    const float* Wr1  = (const float*)d_in[5];
    const float* br1  = (const float*)d_in[6];
    const float* Wo1  = (const float*)d_in[7];
    const float* Wr2  = (const float*)d_in[8];
    const float* br2  = (const float*)d_in[9];
    const float* Wo2  = (const float*)d_in[10];
    float* out = (float*)d_out;

    float* ws      = (float*)d_ws;
    float* h0g     = ws;                        // N
    float* h1g     = ws + N;                    // 8N
    float* cntg    = ws + 9 * N;                // N
    float* agg1p   = ws + 10 * N;               // 4N
    float* agg2p   = ws + 14 * N;               // 32N
    u32*   qoff    = (u32*)(ws + 46 * N);       // 4N
    u32*   qcnt    = (u32*)(ws + 50 * N);       // 4N
    u32*   sortedq = (u32*)(ws + 54 * N);       // E u32 = 13.1 MB (total ~24.2 MB)

    hipLaunchKernelGGL(k_h0,   dim3(256), dim3(256), 0, stream, x, fc1w, fc1b, h0g);
    hipLaunchKernelGGL(k_sort, dim3(512), dim3(512), 0, stream, ei, ea, h0g, sortedq, qoff, qcnt, agg1p);
    hipLaunchKernelGGL(k_g2,   dim3(512), dim3(512), 0, stream, sortedq, qoff, qcnt, agg1p, h0g, Wr1, br1, Wo1, h1g, cntg, agg2p);
    hipLaunchKernelGGL(k_out,  dim3(512), dim3(512), 0, stream, h1g, agg2p, cntg, Wr2, br2, Wo2, out);
}